// Round 6
// baseline (16.415 us; speedup 1.0000x reference)
//
#include <hip/hip_runtime.h>

#define NT      10
#define NBATCH  16
#define SEQ     512
#define KSTEPS  10
#define NC      16               // chunks per batch (all in one block)
#define CL      (SEQ / NC)       // 32 intervals per chunk
#define SPLIT   5                // state-splits per batch
#define SPB     (NT * NT / SPLIT) // 20 states per block
#define THREADS (NC * SPB)       // 320 = 5 waves exactly

// One block = (batch b, states [sp*20, sp*20+20)), all 16 chunks.
// Phase A: stage the batch's 512 times+types in LDS.
// Phase B: thread (c, s) scans chunk c for state s -> affine coeffs in LDS:
//   g_out = A*g_in + B ; integral = C*g_in + D ; loglik = E*g_in + F
// Phase C: threads 0..19 fold the 16 chunks per state, block-reduce,
//          one atomicAdd(out) per block. out zeroed by a 4-byte memset node.

__global__ __launch_bounds__(THREADS) void hawkes_fused(
    const float* __restrict__ times, const int* __restrict__ types,
    const float* __restrict__ Tptr,  const float* __restrict__ mu,
    const float* __restrict__ alpha, const float* __restrict__ beta,
    float* __restrict__ out)
{
    __shared__ float s_time[SEQ];
    __shared__ int   s_ty[SEQ];
    __shared__ float cA[NC][SPB], cB[NC][SPB], cC[NC][SPB],
                     cD[NC][SPB], cE[NC][SPB], cF[NC][SPB];
    __shared__ float s_part[SPB];

    const int blk = blockIdx.x;
    const int b   = blk / SPLIT;
    const int sp  = blk - b * SPLIT;
    const int t   = threadIdx.x;

    const float* bt  = times + b * SEQ;
    const int*   bty = types + b * SEQ;
    #pragma unroll
    for (int i = t; i < SEQ; i += THREADS) { s_time[i] = bt[i]; s_ty[i] = bty[i]; }
    __syncthreads();

    const int c  = t / SPB;            // chunk 0..15
    const int sl = t - c * SPB;        // local state 0..19
    const int s  = sp * SPB + sl;      // global state 0..99
    const int a  = s / NT;             // source type
    const int m  = s - a * NT;         // target type
    const float al  = alpha[a * NT + m];
    const float be  = beta [a * NT + m];
    const float mum = (a == 0) ? mu[m] : 0.f;   // lane (0,m) owns the mu[ty] term

    float A = 1.f, gl = 0.f, C_ = 0.f, D = 0.f, E = 0.f, F = 0.f;
    const int k0 = c * CL;
    float tprev = (c == 0) ? 0.f : s_time[k0 - 1];

    #pragma unroll 8
    for (int i = 0; i < CL; ++i) {
        const float te   = s_time[k0 + i];
        const float h    = (te - tprev) * (1.0f / KSTEPS);
        tprev = te;
        const float x    = be * h;
        const float e1   = __expf(-x);
        const float e10  = __expf(-10.f * x);
        const float gA   = (1.f - e10 * e1) * __builtin_amdgcn_rcpf(1.f - e1);
        const float gB   = 11.f + x * (-55.f + 192.5f * x);
        const float geom = (x > 1e-3f) ? gA : gB;   // sum_{p=0}^{10} e^{-p x}
        const float coef = al * geom * h;
        C_ = fmaf(coef, A,  C_);
        D  = fmaf(coef, gl, D);
        A  *= e10;
        gl *= e10;
        const int ty = s_ty[k0 + i];
        E  = (ty == m) ? fmaf(al, A,  E) : E;        // after decay, before +1 (strict j<k)
        F  = (ty == m) ? (F + fmaf(al, gl, mum)) : F;
        gl += (ty == a) ? 1.f : 0.f;
    }
    if (c == NC - 1) {   // final interval (t_{S-1}, T], quadrature only
        const float h    = (Tptr[0] - tprev) * (1.0f / KSTEPS);
        const float x    = be * h;
        const float e1   = __expf(-x);
        const float e10  = __expf(-10.f * x);
        const float gA   = (1.f - e10 * e1) * __builtin_amdgcn_rcpf(1.f - e1);
        const float gB   = 11.f + x * (-55.f + 192.5f * x);
        const float geom = (x > 1e-3f) ? gA : gB;
        const float coef = al * geom * h;
        C_ = fmaf(coef, A,  C_);
        D  = fmaf(coef, gl, D);
    }

    cA[c][sl] = A;  cB[c][sl] = gl;
    cC[c][sl] = C_; cD[c][sl] = D;
    cE[c][sl] = E;  cF[c][sl] = F;
    __syncthreads();

    if (t < SPB) {   // fold chunks for state t (LDS-resident, conflict-free)
        float g = 0.f, I = 0.f, Lk = 0.f;
        #pragma unroll
        for (int cc = 0; cc < NC; ++cc) {
            I  += fmaf(cC[cc][t], g, cD[cc][t]);
            Lk += fmaf(cE[cc][t], g, cF[cc][t]);
            g   = fmaf(cA[cc][t], g, cB[cc][t]);
        }
        s_part[t] = I - Lk;
    }
    __syncthreads();
    if (t == 0) {
        float S = 0.f;
        #pragma unroll
        for (int i = 0; i < SPB; ++i) S += s_part[i];
        if (sp == 0) {   // per-batch constant quadrature term, added once per batch
            float mus = 0.f;
            #pragma unroll
            for (int i = 0; i < NT; ++i) mus += mu[i];
            S += (float)(KSTEPS + 1) * mus * Tptr[0] * (1.0f / KSTEPS);
        }
        atomicAdd(out, S);
    }
}

extern "C" void kernel_launch(void* const* d_in, const int* in_sizes, int n_in,
                              void* d_out, int out_size, void* d_ws, size_t ws_size,
                              hipStream_t stream) {
    const float* times = (const float*)d_in[0];
    const int*   types = (const int*)d_in[1];
    const float* T     = (const float*)d_in[2];
    const float* mu    = (const float*)d_in[3];
    const float* alpha = (const float*)d_in[4];
    const float* beta  = (const float*)d_in[5];
    float* out = (float*)d_out;

    hipMemsetAsync(out, 0, sizeof(float), stream);   // graph-capturable memset node
    hawkes_fused<<<NBATCH * SPLIT, THREADS, 0, stream>>>(times, types, T, mu,
                                                         alpha, beta, out);
}

// Round 7
// 12.593 us; speedup vs baseline: 1.3035x; 1.3035x over previous
//
#include <hip/hip_runtime.h>

#define NT      10
#define NBATCH  16
#define SEQ     512
#define KSTEPS  10
#define NC      16                // chunks per batch (all in one block)
#define CL      (SEQ / NC)        // 32 intervals per chunk
#define SPLIT   5                 // state-splits per batch
#define SPB     (NT * NT / SPLIT) // 20 states per block
#define THREADS (NC * SPB)        // 320 = 5 waves exactly
#define NBLOCKS (NBATCH * SPLIT)  // 80

// One block = (batch b, states [sp*20, sp*20+20)), all 16 chunks.
// Phase A: stage the batch's 512 times+types in LDS.
// Phase B: thread (c, s) scans chunk c for state s -> affine coeffs in LDS:
//   g_out = A*g_in + B ; integral = C*g_in + D ; loglik = E*g_in + F
// Phase C: threads 0..19 fold the 16 chunks per state in LDS; block writes ONE
//          partial float to ws. K2 (1 block) sums the 80 partials -> out[0].
// No atomics, no memset: ws partials are fully overwritten every call.

__global__ __launch_bounds__(THREADS) void hawkes_fused(
    const float* __restrict__ times, const int* __restrict__ types,
    const float* __restrict__ Tptr,  const float* __restrict__ mu,
    const float* __restrict__ alpha, const float* __restrict__ beta,
    float* __restrict__ partial)
{
    __shared__ float s_time[SEQ];
    __shared__ int   s_ty[SEQ];
    __shared__ float cA[NC][SPB], cB[NC][SPB], cC[NC][SPB],
                     cD[NC][SPB], cE[NC][SPB], cF[NC][SPB];
    __shared__ float s_part[SPB];

    const int blk = blockIdx.x;
    const int b   = blk / SPLIT;
    const int sp  = blk - b * SPLIT;
    const int t   = threadIdx.x;

    const float* bt  = times + b * SEQ;
    const int*   bty = types + b * SEQ;
    #pragma unroll
    for (int i = t; i < SEQ; i += THREADS) { s_time[i] = bt[i]; s_ty[i] = bty[i]; }
    __syncthreads();

    const int c  = t / SPB;            // chunk 0..15
    const int sl = t - c * SPB;        // local state 0..19
    const int s  = sp * SPB + sl;      // global state 0..99
    const int a  = s / NT;             // source type
    const int m  = s - a * NT;         // target type
    const float al  = alpha[a * NT + m];
    const float be  = beta [a * NT + m];
    const float mum = (a == 0) ? mu[m] : 0.f;   // lane (0,m) owns the mu[ty] term

    float A = 1.f, gl = 0.f, C_ = 0.f, D = 0.f, E = 0.f, F = 0.f;
    const int k0 = c * CL;
    float tprev = (c == 0) ? 0.f : s_time[k0 - 1];

    #pragma unroll 8
    for (int i = 0; i < CL; ++i) {
        const float te   = s_time[k0 + i];
        const float h    = (te - tprev) * (1.0f / KSTEPS);
        tprev = te;
        const float x    = be * h;
        const float e1   = __expf(-x);
        const float e10  = __expf(-10.f * x);
        const float gA   = (1.f - e10 * e1) * __builtin_amdgcn_rcpf(1.f - e1);
        const float gB   = 11.f + x * (-55.f + 192.5f * x);
        const float geom = (x > 1e-3f) ? gA : gB;   // sum_{p=0}^{10} e^{-p x}
        const float coef = al * geom * h;
        C_ = fmaf(coef, A,  C_);
        D  = fmaf(coef, gl, D);
        A  *= e10;
        gl *= e10;
        const int ty = s_ty[k0 + i];
        E  = (ty == m) ? fmaf(al, A,  E) : E;        // after decay, before +1 (strict j<k)
        F  = (ty == m) ? (F + fmaf(al, gl, mum)) : F;
        gl += (ty == a) ? 1.f : 0.f;
    }
    if (c == NC - 1) {   // final interval (t_{S-1}, T], quadrature only
        const float h    = (Tptr[0] - tprev) * (1.0f / KSTEPS);
        const float x    = be * h;
        const float e1   = __expf(-x);
        const float e10  = __expf(-10.f * x);
        const float gA   = (1.f - e10 * e1) * __builtin_amdgcn_rcpf(1.f - e1);
        const float gB   = 11.f + x * (-55.f + 192.5f * x);
        const float geom = (x > 1e-3f) ? gA : gB;
        const float coef = al * geom * h;
        C_ = fmaf(coef, A,  C_);
        D  = fmaf(coef, gl, D);
    }

    cA[c][sl] = A;  cB[c][sl] = gl;
    cC[c][sl] = C_; cD[c][sl] = D;
    cE[c][sl] = E;  cF[c][sl] = F;
    __syncthreads();

    if (t < SPB) {   // fold chunks for state t (LDS-resident)
        float g = 0.f, I = 0.f, Lk = 0.f;
        #pragma unroll
        for (int cc = 0; cc < NC; ++cc) {
            I  += fmaf(cC[cc][t], g, cD[cc][t]);
            Lk += fmaf(cE[cc][t], g, cF[cc][t]);
            g   = fmaf(cA[cc][t], g, cB[cc][t]);
        }
        s_part[t] = I - Lk;
    }
    __syncthreads();
    if (t == 0) {
        float S = 0.f;
        #pragma unroll
        for (int i = 0; i < SPB; ++i) S += s_part[i];
        partial[blk] = S;
    }
}

__global__ __launch_bounds__(128) void hawkes_sum(
    const float* __restrict__ partial, const float* __restrict__ mu,
    const float* __restrict__ Tptr, float* __restrict__ out)
{
    const int t = threadIdx.x;
    float S = (t < NBLOCKS) ? partial[t] : 0.f;
    for (int off = 32; off; off >>= 1) S += __shfl_down(S, off);
    __shared__ float red[2];
    if ((t & 63) == 0) red[t >> 6] = S;
    __syncthreads();
    if (t == 0) {
        float mus = 0.f;
        #pragma unroll
        for (int i = 0; i < NT; ++i) mus += mu[i];
        // constant quadrature term: B * (STEPS+1) * sum(mu) * (T/STEPS)
        const float cst = (float)NBATCH * (float)(KSTEPS + 1) * mus * Tptr[0] * (1.0f / KSTEPS);
        out[0] = red[0] + red[1] + cst;
    }
}

extern "C" void kernel_launch(void* const* d_in, const int* in_sizes, int n_in,
                              void* d_out, int out_size, void* d_ws, size_t ws_size,
                              hipStream_t stream) {
    const float* times = (const float*)d_in[0];
    const int*   types = (const int*)d_in[1];
    const float* T     = (const float*)d_in[2];
    const float* mu    = (const float*)d_in[3];
    const float* alpha = (const float*)d_in[4];
    const float* beta  = (const float*)d_in[5];
    float* partial = (float*)d_ws;       // 80 floats, fully overwritten every call
    float* out     = (float*)d_out;

    hawkes_fused<<<NBLOCKS, THREADS, 0, stream>>>(times, types, T, mu, alpha, beta, partial);
    hawkes_sum<<<1, 128, 0, stream>>>(partial, mu, T, out);
}

// Round 8
// 11.494 us; speedup vs baseline: 1.4281x; 1.0955x over previous
//
#include <hip/hip_runtime.h>

#define NT    10
#define NB    16
#define SEQ   512
#define KST   10
#define NCH   32              // chunks per sequence (one per lane in a 32-group)
#define CLEN  (SEQ / NCH)     // 16 intervals per chunk
#define GRP   50              // state-pairs per batch
#define NBLK  (NB * GRP)      // 800 blocks, 1 wave each

// Lane (c, s): scan chunk c (16 intervals) for state s=(a,m), producing the
// affine map over the chunk:  g_out = A*g_in + B ; I = C*g_in + D ; L = E*g_in + F.
// Maps compose associatively -> 5-step shfl_xor butterfly replaces the serial
// fold. With g0 = 0 the per-state totals are just (D_full, F_full).
// Block = 64 lanes = 32 chunks x 2 states. No LDS, no __syncthreads.

__global__ __launch_bounds__(64) void hawkes_scan(
    const float* __restrict__ times, const int* __restrict__ types,
    const float* __restrict__ Tptr,  const float* __restrict__ mu,
    const float* __restrict__ alpha, const float* __restrict__ beta,
    float* __restrict__ partial)
{
    const int blk  = blockIdx.x;
    const int b    = blk / GRP;
    const int grp  = blk - b * GRP;
    const int lane = threadIdx.x;
    const int half = lane >> 5;          // which of the 2 states
    const int c    = lane & 31;          // chunk index
    const int s    = grp * 2 + half;     // state 0..99
    const int a    = s / NT;             // source type
    const int m    = s - a * NT;         // target type

    const float al  = alpha[a * NT + m];
    const float be  = beta [a * NT + m];
    const float mum = (a == 0) ? mu[m] : 0.f;   // state (0,m) owns the mu[ty] term

    // preload this chunk's 16 times + 16 types into VGPRs (64B-aligned float4)
    const float4* tp = (const float4*)(times + b * SEQ + c * CLEN);
    const int4*   yp = (const int4*)  (types + b * SEQ + c * CLEN);
    const float4 T0 = tp[0], T1 = tp[1], T2 = tp[2], T3 = tp[3];
    const int4   Y0 = yp[0], Y1 = yp[1], Y2 = yp[2], Y3 = yp[3];

    // chunk-boundary time t[k0-1]: previous lane's last time (0 for c==0)
    float tprev = __shfl(T3.w, lane - 1, 64);
    if (c == 0) tprev = 0.f;

    float A = 1.f, B = 0.f, C = 0.f, D = 0.f, E = 0.f, F = 0.f;

#define STEP(TE, TY)                                                          \
    {                                                                         \
        const float h    = ((TE) - tprev) * (1.0f / KST);                     \
        tprev = (TE);                                                         \
        const float x    = be * h;                                            \
        const float e1   = __expf(-x);                                        \
        const float e10  = __expf(-10.f * x);                                 \
        const float gA   = (1.f - e10 * e1) * __builtin_amdgcn_rcpf(1.f - e1);\
        const float gB   = 11.f + x * (-55.f + 192.5f * x);                   \
        const float geom = (x > 1e-3f) ? gA : gB;                             \
        const float coef = al * geom * h;                                     \
        C = fmaf(coef, A, C);                                                 \
        D = fmaf(coef, B, D);                                                 \
        A *= e10;                                                             \
        B *= e10;                                                             \
        E = ((TY) == m) ? fmaf(al, A, E) : E;                                 \
        F = ((TY) == m) ? (F + fmaf(al, B, mum)) : F;                         \
        B += ((TY) == a) ? 1.f : 0.f;                                         \
    }

    STEP(T0.x, Y0.x) STEP(T0.y, Y0.y) STEP(T0.z, Y0.z) STEP(T0.w, Y0.w)
    STEP(T1.x, Y1.x) STEP(T1.y, Y1.y) STEP(T1.z, Y1.z) STEP(T1.w, Y1.w)
    STEP(T2.x, Y2.x) STEP(T2.y, Y2.y) STEP(T2.z, Y2.z) STEP(T2.w, Y2.w)
    STEP(T3.x, Y3.x) STEP(T3.y, Y3.y) STEP(T3.z, Y3.z) STEP(T3.w, Y3.w)
#undef STEP

    if (c == NCH - 1) {   // final interval (t_{S-1}, T]: quadrature only
        const float h    = (Tptr[0] - tprev) * (1.0f / KST);
        const float x    = be * h;
        const float e1   = __expf(-x);
        const float e10  = __expf(-10.f * x);
        const float gA   = (1.f - e10 * e1) * __builtin_amdgcn_rcpf(1.f - e1);
        const float gB   = 11.f + x * (-55.f + 192.5f * x);
        const float geom = (x > 1e-3f) ? gA : gB;
        const float coef = al * geom * h;
        C = fmaf(coef, A, C);
        D = fmaf(coef, B, D);
    }

    // butterfly composition over the 32 chunks (order: chunk 0 first)
    #pragma unroll
    for (int msk = 1; msk < 32; msk <<= 1) {
        const float pA = __shfl_xor(A, msk, 32);
        const float pB = __shfl_xor(B, msk, 32);
        const float pC = __shfl_xor(C, msk, 32);
        const float pD = __shfl_xor(D, msk, 32);
        const float pE = __shfl_xor(E, msk, 32);
        const float pF = __shfl_xor(F, msk, 32);
        const bool e = ((lane & msk) == 0);   // self is the earlier block
        const float Af = e ? A : pA, Bf = e ? B : pB, Cf = e ? C : pC,
                    Df = e ? D : pD, Ef = e ? E : pE, Ff = e ? F : pF;
        const float Ag = e ? pA : A, Bg = e ? pB : B, Cg = e ? pC : C,
                    Dg = e ? pD : D, Eg = e ? pE : E, Fg = e ? pF : F;
        A = Ag * Af;
        B = fmaf(Ag, Bf, Bg);
        C = fmaf(Cg, Af, Cf);
        D = Df + fmaf(Cg, Bf, Dg);
        E = fmaf(Eg, Af, Ef);
        F = Ff + fmaf(Eg, Bf, Fg);
    }

    const float v  = D - F;                 // per-state (integral - loglik), g0 = 0
    const float v2 = __shfl(v, lane ^ 32, 64);
    if (lane == 0) partial[blk] = v + v2;
}

__global__ __launch_bounds__(256) void hawkes_sum(
    const float* __restrict__ partial, const float* __restrict__ mu,
    const float* __restrict__ Tptr, float* __restrict__ out)
{
    const int t = threadIdx.x;
    float S = 0.f;
    for (int i = t; i < NBLK; i += 256) S += partial[i];
    for (int off = 32; off; off >>= 1) S += __shfl_down(S, off, 64);
    __shared__ float red[4];
    if ((t & 63) == 0) red[t >> 6] = S;
    __syncthreads();
    if (t == 0) {
        float mus = 0.f;
        #pragma unroll
        for (int i = 0; i < NT; ++i) mus += mu[i];
        // constant quadrature term: B * (STEPS+1) * sum(mu) * (T/STEPS)
        const float cst = (float)NB * (float)(KST + 1) * mus * Tptr[0] * (1.0f / KST);
        out[0] = red[0] + red[1] + red[2] + red[3] + cst;
    }
}

extern "C" void kernel_launch(void* const* d_in, const int* in_sizes, int n_in,
                              void* d_out, int out_size, void* d_ws, size_t ws_size,
                              hipStream_t stream) {
    const float* times = (const float*)d_in[0];
    const int*   types = (const int*)d_in[1];
    const float* T     = (const float*)d_in[2];
    const float* mu    = (const float*)d_in[3];
    const float* alpha = (const float*)d_in[4];
    const float* beta  = (const float*)d_in[5];
    float* partial = (float*)d_ws;     // 800 floats, fully overwritten every call
    float* out     = (float*)d_out;

    hawkes_scan<<<NBLK, 64, 0, stream>>>(times, types, T, mu, alpha, beta, partial);
    hawkes_sum<<<1, 256, 0, stream>>>(partial, mu, T, out);
}